// Round 3
// baseline (225.776 us; speedup 1.0000x reference)
//
#include <hip/hip_runtime.h>

// DilatedAttention b=2,h=16,s=8192,d=64; W=[4,8,16], R=[1,2,4] -> L=4 per group.
// A 16-position span is self-contained for all 3 groups. One WAVE per span:
// no LDS, no __syncthreads. Lane l: group g=l>>4 owns rows {4t+g}, d-chunk
// c=l&15 (floats 4c..4c+3). Scores via in-lane dot4 + butterfly reduce
// (broadcasts over the 16 c-lanes, so softmax rows are complete per-lane).
// Cross-row K/V fetched with shfl_xor(m<<4). Register double-buffer prefetch
// hides HBM latency; group participation is branchless (zero weights).

#define D      64
#define S_SEQ  8192
#define SPAN   16
#define NBLK   512
#define NTHR   256

__device__ __forceinline__ float dot4(float4 a, float4 b) {
    return fmaf(a.x, b.x, fmaf(a.y, b.y, fmaf(a.z, b.z, a.w * b.w)));
}

__device__ __forceinline__ float4 shfl4(float4 x, int m) {
    float4 r;
    r.x = __shfl_xor(x.x, m, 64);
    r.y = __shfl_xor(x.y, m, 64);
    r.z = __shfl_xor(x.z, m, 64);
    r.w = __shfl_xor(x.w, m, 64);
    return r;
}

__device__ __forceinline__ float4 smax4(float a, float b, float c, float d) {
    float m = fmaxf(fmaxf(a, b), fmaxf(c, d));
    float ea = __expf(a - m), eb = __expf(b - m);
    float ec = __expf(c - m), ed = __expf(d - m);
    float inv = 1.0f / (ea + eb + ec + ed);
    return make_float4(ea * inv, eb * inv, ec * inv, ed * inv);
}

__device__ __forceinline__ void axpy4(float4& o, float s, float4 v) {
    o.x = fmaf(s, v.x, o.x);
    o.y = fmaf(s, v.y, o.y);
    o.z = fmaf(s, v.z, o.z);
    o.w = fmaf(s, v.w, o.w);
}

__device__ __forceinline__ void span_load(const float4* __restrict__ q4,
                                          const float4* __restrict__ k4,
                                          const float4* __restrict__ v4,
                                          long long f4base, int l,
                                          float4 qq[4], float4 kk[4], float4 vv[4]) {
#pragma unroll
    for (int t = 0; t < 4; ++t) {
        qq[t] = q4[f4base + t * 64 + l];
        kk[t] = k4[f4base + t * 64 + l];
        vv[t] = v4[f4base + t * 64 + l];
    }
}

__device__ __forceinline__ void span_compute(const float4 qq[4], const float4 kk[4],
                                             const float4 vv[4],
                                             float4* __restrict__ o4,
                                             long long f4base, int l,
                                             float w0, float w1e, float w2e) {
    // ---- scores: 32 raw partial dots per lane ----
    // sc[m*4+t]        : g0 diag, row i=4t+g vs j=4t+(g^m)              (m=0..3)
    // sc[16+ti]        : m=0 off-diag (t_j=ti^1)  -> g1/g2 reuse
    // sc[20+ti]        : m=2 off-diag (t_j=ti^1)  -> g1
    // sc[24+ti*2+e]    : m=0, t_j=ti^(2+e)        -> g2
    float sc[32];
#pragma unroll
    for (int tj = 0; tj < 4; ++tj) {
        float4 k0 = kk[tj];
        float4 k1 = shfl4(k0, 16);
        float4 k2 = shfl4(k0, 32);
        float4 k3 = shfl4(k0, 48);
        sc[tj]                = dot4(qq[tj],     k0);
        sc[16 + (tj ^ 1)]     = dot4(qq[tj ^ 1], k0);
        sc[24 + (tj ^ 2) * 2] = dot4(qq[tj ^ 2], k0);
        sc[24 + (tj ^ 3) * 2 + 1] = dot4(qq[tj ^ 3], k0);
        sc[4 + tj]            = dot4(qq[tj],     k1);
        sc[8 + tj]            = dot4(qq[tj],     k2);
        sc[20 + (tj ^ 1)]     = dot4(qq[tj ^ 1], k2);
        sc[12 + tj]           = dot4(qq[tj],     k3);
    }
    // butterfly over the 16 d-chunk lanes: reduce + broadcast; scale d^-0.5
#pragma unroll
    for (int i = 0; i < 32; ++i) {
        float s = sc[i];
        s += __shfl_xor(s, 1, 64);
        s += __shfl_xor(s, 2, 64);
        s += __shfl_xor(s, 4, 64);
        s += __shfl_xor(s, 8, 64);
        sc[i] = s * 0.125f;
    }

    float4 o[4];
#pragma unroll
    for (int t = 0; t < 4; ++t) o[t] = make_float4(0.f, 0.f, 0.f, 0.f);

    // ---- group 2 (w=16, idx {0,4,8,12}): valid in lane-group 0 only (w2e) ----
#pragma unroll
    for (int ti = 0; ti < 4; ++ti) {
        float4 p = smax4(sc[ti], sc[16 + ti], sc[24 + ti * 2], sc[24 + ti * 2 + 1]);
        axpy4(o[ti], w2e * p.x, vv[ti]);
        axpy4(o[ti], w2e * p.y, vv[ti ^ 1]);
        axpy4(o[ti], w2e * p.z, vv[ti ^ 2]);
        axpy4(o[ti], w2e * p.w, vv[ti ^ 3]);
    }

    // ---- group 1 (w=8, idx {0,2,4,6}): valid in lane-groups {0,2} (w1e) ----
    float4 v2[4];
#pragma unroll
    for (int t = 0; t < 4; ++t) v2[t] = shfl4(vv[t], 32);
#pragma unroll
    for (int ti = 0; ti < 4; ++ti) {
        float4 p = smax4(sc[ti], sc[16 + ti], sc[8 + ti], sc[20 + ti]);
        axpy4(o[ti], w1e * p.x, vv[ti]);
        axpy4(o[ti], w1e * p.y, vv[ti ^ 1]);
        axpy4(o[ti], w1e * p.z, v2[ti]);
        axpy4(o[ti], w1e * p.w, v2[ti ^ 1]);
    }

    // ---- group 0 (w=4, r=1): all positions ----
#pragma unroll
    for (int t = 0; t < 4; ++t) {
        float4 p = smax4(sc[t], sc[4 + t], sc[8 + t], sc[12 + t]);
        float4 v1 = shfl4(vv[t], 16);
        float4 v3 = shfl4(vv[t], 48);
        axpy4(o[t], w0 * p.x, vv[t]);
        axpy4(o[t], w0 * p.y, v1);
        axpy4(o[t], w0 * p.z, v2[t]);
        axpy4(o[t], w0 * p.w, v3);
    }

#pragma unroll
    for (int t = 0; t < 4; ++t) o4[f4base + t * 64 + l] = o[t];
}

__global__ __launch_bounds__(NTHR, 2) void dilated_attn_kernel(
    const float* __restrict__ q, const float* __restrict__ k,
    const float* __restrict__ v, const float* __restrict__ alpha,
    float* __restrict__ out, int tot_spans) {
    const int l = threadIdx.x & 63;
    const int g = l >> 4;
    const int wave = blockIdx.x * (blockDim.x >> 6) + (threadIdx.x >> 6);
    const int nW = gridDim.x * (blockDim.x >> 6);

    float a0 = alpha[0], a1 = alpha[1], a2 = alpha[2];
    float am = fmaxf(a0, fmaxf(a1, a2));
    float e0 = __expf(a0 - am), e1 = __expf(a1 - am), e2 = __expf(a2 - am);
    float inv = 1.0f / (e0 + e1 + e2);
    const float w0 = e0 * inv;
    const float w1e = (g & 1) ? 0.f : e1 * inv;
    const float w2e = (g == 0) ? e2 * inv : 0.f;

    const float4* q4 = (const float4*)q;
    const float4* k4 = (const float4*)k;
    const float4* v4 = (const float4*)v;
    float4* o4 = (float4*)out;

    float4 qa[4], ka[4], va[4], qb[4], kb[4], vb[4];

    int sp = wave;
    if (sp >= tot_spans) return;
    span_load(q4, k4, v4, (long long)sp * 256, l, qa, ka, va);
    while (true) {
        const int sp1 = sp + nW;
        if (sp1 < tot_spans)
            span_load(q4, k4, v4, (long long)sp1 * 256, l, qb, kb, vb);
        span_compute(qa, ka, va, o4, (long long)sp * 256, l, w0, w1e, w2e);
        if (sp1 >= tot_spans) return;

        const int sp2 = sp1 + nW;
        if (sp2 < tot_spans)
            span_load(q4, k4, v4, (long long)sp2 * 256, l, qa, ka, va);
        span_compute(qb, kb, vb, o4, (long long)sp1 * 256, l, w0, w1e, w2e);
        if (sp2 >= tot_spans) return;
        sp = sp2;
    }
}

extern "C" void kernel_launch(void* const* d_in, const int* in_sizes, int n_in,
                              void* d_out, int out_size, void* d_ws, size_t ws_size,
                              hipStream_t stream) {
    const float* q = (const float*)d_in[0];
    const float* k = (const float*)d_in[1];
    const float* v = (const float*)d_in[2];
    const float* alpha = (const float*)d_in[3];
    float* out = (float*)d_out;

    const int BH = in_sizes[0] / (S_SEQ * D);        // 32
    const int tot_spans = BH * (S_SEQ / SPAN);       // 16384
    hipLaunchKernelGGL(dilated_attn_kernel, dim3(NBLK), dim3(NTHR), 0, stream,
                       q, k, v, alpha, out, tot_spans);
}

// Round 4
// 218.084 us; speedup vs baseline: 1.0353x; 1.0353x over previous
//
#include <hip/hip_runtime.h>

// DilatedAttention b=2,h=16,s=8192,d=64; W=[4,8,16], R=[1,2,4] -> L=4 per group.
// A 16-position span is self-contained for all 3 groups. ONE WAVE PER SPAN,
// 16384 waves total: no LDS, no barriers, no persistent loop — TLP (16
// waves/CU at 128 VGPR) hides load + shuffle + exp latency.
// Lane l: group g=l>>4 owns rows {4t+g}, d-chunk c=l&15 (floats 4c..4c+3).
// Scores: in-lane dot4 + 4-stage butterfly over the 16 c-lanes (reduces AND
// broadcasts). Cross-row K/V via shfl_xor(m<<4). Group participation is
// branchless (zero weight in non-participating lane-groups).

#define D      64
#define S_SEQ  8192
#define SPAN   16
#define NTHR   256

__device__ __forceinline__ float dot4(float4 a, float4 b) {
    return fmaf(a.x, b.x, fmaf(a.y, b.y, fmaf(a.z, b.z, a.w * b.w)));
}

__device__ __forceinline__ float4 shfl4(float4 x, int m) {
    float4 r;
    r.x = __shfl_xor(x.x, m, 64);
    r.y = __shfl_xor(x.y, m, 64);
    r.z = __shfl_xor(x.z, m, 64);
    r.w = __shfl_xor(x.w, m, 64);
    return r;
}

__device__ __forceinline__ float4 smax4(float a, float b, float c, float d) {
    float m = fmaxf(fmaxf(a, b), fmaxf(c, d));
    float ea = __expf(a - m), eb = __expf(b - m);
    float ec = __expf(c - m), ed = __expf(d - m);
    float inv = 1.0f / (ea + eb + ec + ed);
    return make_float4(ea * inv, eb * inv, ec * inv, ed * inv);
}

__device__ __forceinline__ void axpy4(float4& o, float s, float4 v) {
    o.x = fmaf(s, v.x, o.x);
    o.y = fmaf(s, v.y, o.y);
    o.z = fmaf(s, v.z, o.z);
    o.w = fmaf(s, v.w, o.w);
}

__global__ __launch_bounds__(NTHR, 4) void dilated_attn_kernel(
    const float* __restrict__ q, const float* __restrict__ k,
    const float* __restrict__ v, const float* __restrict__ alpha,
    float* __restrict__ out, int tot_spans) {
    const int l = threadIdx.x & 63;
    const int g = l >> 4;
    const int sp = blockIdx.x * (NTHR >> 6) + (threadIdx.x >> 6);
    if (sp >= tot_spans) return;
    const long long f4base = (long long)sp * (SPAN * D / 4);

    // ---- issue all 12 global loads up front (q,k,v: 4 float4 each) ----
    float4 qq[4], kk[4], vv[4];
    {
        const float4* q4 = (const float4*)q;
        const float4* k4 = (const float4*)k;
        const float4* v4 = (const float4*)v;
#pragma unroll
        for (int t = 0; t < 4; ++t) {
            qq[t] = q4[f4base + t * 64 + l];
            kk[t] = k4[f4base + t * 64 + l];
            vv[t] = v4[f4base + t * 64 + l];
        }
    }

    // mixture weights (group participation folded in, branchless per lane-group)
    float a0 = alpha[0], a1 = alpha[1], a2 = alpha[2];
    float am = fmaxf(a0, fmaxf(a1, a2));
    float e0 = __expf(a0 - am), e1 = __expf(a1 - am), e2 = __expf(a2 - am);
    float inv = 1.0f / (e0 + e1 + e2);
    const float w0 = e0 * inv;
    const float w1e = (g & 1) ? 0.f : e1 * inv;
    const float w2e = (g == 0) ? e2 * inv : 0.f;

    // ---- scores: 32 raw partial dots per lane ----
    // sc[m*4+t]     : g0, row i=4t+g vs j=4t+(g^m)      (m=0..3)
    // sc[16+ti]     : m=0 off-diag (t_j=ti^1)           (g1/g2)
    // sc[20+ti]     : m=2 off-diag (t_j=ti^1)           (g1)
    // sc[24+ti*2+e] : m=0, t_j=ti^(2+e)                 (g2)
    float sc[32];
#pragma unroll
    for (int tj = 0; tj < 4; ++tj) {
        float4 k0 = kk[tj];
        float4 k1 = shfl4(k0, 16);
        float4 k2 = shfl4(k0, 32);
        float4 k3 = shfl4(k0, 48);
        sc[tj]                    = dot4(qq[tj],     k0);
        sc[16 + (tj ^ 1)]         = dot4(qq[tj ^ 1], k0);
        sc[24 + (tj ^ 2) * 2]     = dot4(qq[tj ^ 2], k0);
        sc[24 + (tj ^ 3) * 2 + 1] = dot4(qq[tj ^ 3], k0);
        sc[4 + tj]                = dot4(qq[tj],     k1);
        sc[8 + tj]                = dot4(qq[tj],     k2);
        sc[20 + (tj ^ 1)]         = dot4(qq[tj ^ 1], k2);
        sc[12 + tj]               = dot4(qq[tj],     k3);
    }
    // butterfly over the 16 d-chunk lanes: reduce + broadcast; scale d^-0.5
#pragma unroll
    for (int i = 0; i < 32; ++i) {
        float s = sc[i];
        s += __shfl_xor(s, 1, 64);
        s += __shfl_xor(s, 2, 64);
        s += __shfl_xor(s, 4, 64);
        s += __shfl_xor(s, 8, 64);
        sc[i] = s * 0.125f;
    }

    float4 o[4];
#pragma unroll
    for (int t = 0; t < 4; ++t) o[t] = make_float4(0.f, 0.f, 0.f, 0.f);

    // ---- group 2 (w=16, idx {0,4,8,12}): valid in lane-group 0 only ----
#pragma unroll
    for (int ti = 0; ti < 4; ++ti) {
        float4 p = smax4(sc[ti], sc[16 + ti], sc[24 + ti * 2], sc[24 + ti * 2 + 1]);
        axpy4(o[ti], w2e * p.x, vv[ti]);
        axpy4(o[ti], w2e * p.y, vv[ti ^ 1]);
        axpy4(o[ti], w2e * p.z, vv[ti ^ 2]);
        axpy4(o[ti], w2e * p.w, vv[ti ^ 3]);
    }

    // ---- group 1 (w=8, idx {0,2,4,6}): valid in lane-groups {0,2} ----
    float4 v2[4];
#pragma unroll
    for (int t = 0; t < 4; ++t) v2[t] = shfl4(vv[t], 32);
#pragma unroll
    for (int ti = 0; ti < 4; ++ti) {
        float4 p = smax4(sc[ti], sc[16 + ti], sc[8 + ti], sc[20 + ti]);
        axpy4(o[ti], w1e * p.x, vv[ti]);
        axpy4(o[ti], w1e * p.y, vv[ti ^ 1]);
        axpy4(o[ti], w1e * p.z, v2[ti]);
        axpy4(o[ti], w1e * p.w, v2[ti ^ 1]);
    }

    // ---- group 0 (w=4, r=1): all positions ----
#pragma unroll
    for (int t = 0; t < 4; ++t) {
        float4 p = smax4(sc[t], sc[4 + t], sc[8 + t], sc[12 + t]);
        float4 v1 = shfl4(vv[t], 16);
        float4 v3 = shfl4(vv[t], 48);
        axpy4(o[t], w0 * p.x, vv[t]);
        axpy4(o[t], w0 * p.y, v1);
        axpy4(o[t], w0 * p.z, v2[t]);
        axpy4(o[t], w0 * p.w, v3);
    }

    float4* o4 = (float4*)out;
#pragma unroll
    for (int t = 0; t < 4; ++t) o4[f4base + t * 64 + l] = o[t];
}

extern "C" void kernel_launch(void* const* d_in, const int* in_sizes, int n_in,
                              void* d_out, int out_size, void* d_ws, size_t ws_size,
                              hipStream_t stream) {
    const float* q = (const float*)d_in[0];
    const float* k = (const float*)d_in[1];
    const float* v = (const float*)d_in[2];
    const float* alpha = (const float*)d_in[3];
    float* out = (float*)d_out;

    const int BH = in_sizes[0] / (S_SEQ * D);        // 32
    const int tot_spans = BH * (S_SEQ / SPAN);       // 16384
    const int wpb = NTHR / 64;                       // 4 waves per block
    const int nblk = (tot_spans + wpb - 1) / wpb;    // 4096 blocks
    hipLaunchKernelGGL(dilated_attn_kernel, dim3(nblk), dim3(NTHR), 0, stream,
                       q, k, v, alpha, out, tot_spans);
}

// Round 6
// 216.627 us; speedup vs baseline: 1.0422x; 1.0067x over previous
//
#include <hip/hip_runtime.h>

// DilatedAttention b=2,h=16,s=8192,d=64; W=[4,8,16], R=[1,2,4] -> L=4/group.
// 16-span self-contained; ONE WAVE PER SPAN via MFMA (16x16x32 bf16, split
// hi/lo operands for ~fp32 accuracy). Softmax in fp32 on the C-layout with 28
// shuffles; P goes C->A layout through per-wave LDS (no __syncthreads).
// PV: K padded 16->32, A(P) zeroed for k>=16 so duplicated B(V) is harmless.
// R5 bug fixed: P needs block-diagonal WINDOW masks (g0: j in [4g,4g+4);
// g1: j even AND j in [8(g>>1),+8)) — lane-constant, branchless.

#define S_SEQ 8192
#define D     64
#define NTHR  256

typedef __attribute__((ext_vector_type(8))) short bf16x8;
typedef __attribute__((ext_vector_type(4))) float f32x4;

union B8 { unsigned u[4]; bf16x8 v; };

// pack truncated-bf16 of (a,b) into one dword (a->low), residuals out
static __device__ __forceinline__ unsigned pk_hi(float a, float b, float& ra, float& rb) {
    unsigned ua = __float_as_uint(a), ub = __float_as_uint(b);
    ra = a - __uint_as_float(ua & 0xFFFF0000u);
    rb = b - __uint_as_float(ub & 0xFFFF0000u);
    return (ua >> 16) | (ub & 0xFFFF0000u);
}
static __device__ __forceinline__ unsigned pk(float a, float b) {
    return (__float_as_uint(a) >> 16) | (__float_as_uint(b) & 0xFFFF0000u);
}

// 8 consecutive floats -> hi/lo bf16x8 fragments
static __device__ __forceinline__ void mk_frag(const float* f, B8& hi, B8& lo) {
    float r[8];
#pragma unroll
    for (int i = 0; i < 4; ++i) hi.u[i] = pk_hi(f[2 * i], f[2 * i + 1], r[2 * i], r[2 * i + 1]);
#pragma unroll
    for (int i = 0; i < 4; ++i) lo.u[i] = pk(r[2 * i], r[2 * i + 1]);
}

__global__ __launch_bounds__(NTHR) void dilated_attn_kernel(
    const float* __restrict__ q, const float* __restrict__ k,
    const float* __restrict__ v, const float* __restrict__ alpha,
    float* __restrict__ out) {
    // per-wave P buffer: 16 rows x 20 dwords (stride 20 -> <=2-way banks)
    __shared__ float lp[4][16 * 20];

    const int l  = threadIdx.x & 63;
    const int wv = threadIdx.x >> 6;
    const int sp = blockIdx.x * 4 + wv;              // one span per wave
    const int jc = l & 15;                           // col lane (j / n / m)
    const int g  = l >> 4;                           // quarter-wave
    const long long base = (long long)sp * 1024;     // floats (16 pos x 64 d)

    // ---- Q/K fragment loads (A layout: row jc, d-offset g*8 (+32 chunk 1)) ----
    const float4* q4 = (const float4*)(q + base);
    const float4* k4 = (const float4*)(k + base);
    float4 qv[4], kv[4];
#pragma unroll
    for (int c = 0; c < 2; ++c) {
        qv[2 * c]     = q4[jc * 16 + g * 2 + 8 * c];
        qv[2 * c + 1] = q4[jc * 16 + g * 2 + 8 * c + 1];
        kv[2 * c]     = k4[jc * 16 + g * 2 + 8 * c];
        kv[2 * c + 1] = k4[jc * 16 + g * 2 + 8 * c + 1];
    }

    // alpha softmax -> mixture weights, with per-lane window masks folded in
    float a0 = alpha[0], a1 = alpha[1], a2 = alpha[2];
    float am = fmaxf(a0, fmaxf(a1, a2));
    float e0a = __expf(a0 - am), e1a = __expf(a1 - am), e2a = __expf(a2 - am);
    float inv = 1.0f / (e0a + e1a + e2a);
    // group 0: row i in [4g,4g+4) -> columns j must satisfy (j>>2)==g
    const float w0m = ((jc >> 2) == g) ? e0a * inv : 0.f;
    // group 1: j even AND (j>>3)==(i>>3)==(g>>1)
    const float jm1 = (((jc & 1) == 0) && ((jc >> 3) == (g >> 1))) ? e1a * inv : 0.f;
    // group 2: window = whole span; j%4==0
    const float jm2 = (jc & 3) ? 0.f : e2a * inv;

    // ---- QK^T: S[i][j], split-bf16 3-term (hi*hi + hi*lo + lo*hi) ----
    B8 qh[2], ql[2], kh[2], kl[2];
#pragma unroll
    for (int c = 0; c < 2; ++c) {
        mk_frag((const float*)&qv[2 * c], qh[c], ql[c]);
        mk_frag((const float*)&kv[2 * c], kh[c], kl[c]);
    }
    f32x4 S = {0.f, 0.f, 0.f, 0.f};
    S = __builtin_amdgcn_mfma_f32_16x16x32_bf16(qh[0].v, kh[0].v, S, 0, 0, 0);
    S = __builtin_amdgcn_mfma_f32_16x16x32_bf16(qh[1].v, kh[1].v, S, 0, 0, 0);
    S = __builtin_amdgcn_mfma_f32_16x16x32_bf16(qh[0].v, kl[0].v, S, 0, 0, 0);
    S = __builtin_amdgcn_mfma_f32_16x16x32_bf16(qh[1].v, kl[1].v, S, 0, 0, 0);
    S = __builtin_amdgcn_mfma_f32_16x16x32_bf16(ql[0].v, kh[0].v, S, 0, 0, 0);
    S = __builtin_amdgcn_mfma_f32_16x16x32_bf16(ql[1].v, kh[1].v, S, 0, 0, 0);

    // ---- V loads (B layout; k-rows duplicated to upper quarters, A masks) ----
    const float* vb = v + base + jc;
    float vf[4][8];
#pragma unroll
    for (int c = 0; c < 4; ++c)
#pragma unroll
        for (int jj = 0; jj < 8; ++jj)
            vf[c][jj] = vb[((g & 1) * 8 + jj) * 64 + 16 * c];

    // ---- softmax per group on C layout (row i=g*4+r, col j=jc) ----
    float* lpr = lp[wv];
#pragma unroll
    for (int r = 0; r < 4; ++r) {
        float s = S[r] * 0.125f;                      // d^-0.5
        // group 0: denominator over jc's 4-aligned group (== window(i) when masked)
        float m0 = fmaxf(s, __shfl_xor(s, 1, 64));
        m0 = fmaxf(m0, __shfl_xor(m0, 2, 64));
        float e0 = __expf(s - m0);
        float t0 = e0 + __shfl_xor(e0, 1, 64);
        t0 += __shfl_xor(t0, 2, 64);
        float P = w0m * e0 / t0;
        if ((r & 1) == 0) {                           // group 1: rows i even
            float m1 = fmaxf(s, __shfl_xor(s, 2, 64));
            m1 = fmaxf(m1, __shfl_xor(m1, 4, 64));
            float e1 = __expf(s - m1);
            float t1 = e1 + __shfl_xor(e1, 2, 64);
            t1 += __shfl_xor(t1, 4, 64);
            P += jm1 * e1 / t1;
        }
        if (r == 0) {                                 // group 2: rows i%4==0
            float m2 = fmaxf(s, __shfl_xor(s, 4, 64));
            m2 = fmaxf(m2, __shfl_xor(m2, 8, 64));
            float e2 = __expf(s - m2);
            float t2 = e2 + __shfl_xor(e2, 4, 64);
            t2 += __shfl_xor(t2, 8, 64);
            P += jm2 * e2 / t2;
        }
        lpr[(g * 4 + r) * 20 + jc] = P;               // weighted+masked P, fp32
    }

    // ---- P: C->A layout via LDS (same wave: DS ops execute in order) ----
    float pf[8];
    *(float4*)&pf[0] = *(const float4*)&lpr[jc * 20 + (g & 1) * 8];
    *(float4*)&pf[4] = *(const float4*)&lpr[jc * 20 + (g & 1) * 8 + 4];
    B8 ph, pl2;
    mk_frag(pf, ph, pl2);
    if (g >= 2) {                                     // zero A for k>=16 (K pad)
#pragma unroll
        for (int i = 0; i < 4; ++i) { ph.u[i] = 0; pl2.u[i] = 0; }
    }

    // ---- PV: 4 d-chunks, 3-term split ----
    f32x4 acc[4];
#pragma unroll
    for (int c = 0; c < 4; ++c) {
        B8 vh, vl;
        mk_frag(vf[c], vh, vl);
        f32x4 a = {0.f, 0.f, 0.f, 0.f};
        a = __builtin_amdgcn_mfma_f32_16x16x32_bf16(ph.v,  vh.v, a, 0, 0, 0);
        a = __builtin_amdgcn_mfma_f32_16x16x32_bf16(ph.v,  vl.v, a, 0, 0, 0);
        a = __builtin_amdgcn_mfma_f32_16x16x32_bf16(pl2.v, vh.v, a, 0, 0, 0);
        acc[c] = a;
    }

    // ---- store (C layout: row g*4+r, col jc+16c) ----
    float* ob = out + base + jc;
#pragma unroll
    for (int c = 0; c < 4; ++c)
#pragma unroll
        for (int r = 0; r < 4; ++r)
            ob[(g * 4 + r) * 64 + 16 * c] = acc[c][r];
}

extern "C" void kernel_launch(void* const* d_in, const int* in_sizes, int n_in,
                              void* d_out, int out_size, void* d_ws, size_t ws_size,
                              hipStream_t stream) {
    const float* q = (const float*)d_in[0];
    const float* k = (const float*)d_in[1];
    const float* v = (const float*)d_in[2];
    const float* alpha = (const float*)d_in[3];
    float* out = (float*)d_out;

    const int BH = in_sizes[0] / (S_SEQ * D);          // 32
    const int tot_spans = BH * (S_SEQ / 16);           // 16384
    hipLaunchKernelGGL(dilated_attn_kernel, dim3(tot_spans / 4), dim3(NTHR), 0,
                       stream, q, k, v, alpha, out);
}